// Round 9
// baseline (4062.508 us; speedup 1.0000x reference)
//
#include <hip/hip_runtime.h>
#include <hip/hip_bf16.h>

typedef __hip_bfloat16 hbf16;
typedef __attribute__((ext_vector_type(8))) short bfrag8;
typedef __attribute__((ext_vector_type(4))) short short4v;
typedef __attribute__((ext_vector_type(4))) float f32x4;

#define BATCH 16
#define HH 512
#define WW 512
#define HWSZ (HH * WW)
#define NCHN 16
// Fused predictor: 32x32 output tile per block, halo recompute.
// act1 tile 46x46 (halo 7); buffers [2 half][46][46][8ci] bf16 = 67.7 KB each.
#define BS 46
#define FIN 48

__device__ __forceinline__ float bf2f(short s) {
    union { unsigned u; float f; } c;
    c.u = ((unsigned)(unsigned short)s) << 16;
    return c.f;
}
__device__ __forceinline__ short f2bf(float f) {
    hbf16 h = __float2bfloat16(f);
    return *(short*)&h;
}

// ---------------------------------------------------------------------------
// Block-wide sum reduction (256 threads = 4 waves of 64)
// ---------------------------------------------------------------------------
__device__ __forceinline__ float blockSum(float v) {
#pragma unroll
    for (int o = 32; o > 0; o >>= 1) v += __shfl_down(v, o, 64);
    __shared__ float sh[4];
    const int lane = threadIdx.x & 63, wid = threadIdx.x >> 6;
    if (lane == 0) sh[wid] = v;
    __syncthreads();
    float r = 0.f;
    if (threadIdx.x == 0) r = sh[0] + sh[1] + sh[2] + sh[3];
    __syncthreads();
    return r;
}

// ---------------------------------------------------------------------------
// One conv16 layer inside the fused kernel: in LDS buffer -> out LDS buffer.
// S = output tile extent, hal = halo of the OUTPUT tile (global origin =
// tile_origin - hal). MFMA mapping identical to the HW-verified R7 kernel:
// k_global = s*32 + grp*8 + j ; koff = k>>4 (tap), ci = k&15.
// Writes are masked to 0 outside the 512x512 image (zero-pad semantics),
// always stored (never skipped) to avoid stale ping-pong data.
// ---------------------------------------------------------------------------
__device__ __forceinline__ void conv16_layer(
    const short* __restrict__ inb, short* __restrict__ outb,
    int S, int hal, const float* __restrict__ w, const float* __restrict__ bias,
    int lane, int wv, int ty0, int tx0)
{
    const int arow = lane & 15, grp = lane >> 4, lx = lane & 15;
    const int half = grp & 1, cib = half * 8, kofb = grp >> 1;
    bfrag8 af[5];
#pragma unroll
    for (int s = 0; s < 5; ++s) {
        const int koff = 2 * s + kofb;
#pragma unroll
        for (int j = 0; j < 8; ++j)
            af[s][j] = (koff < 9) ? f2bf(w[(arow * 16 + cib + j) * 9 + koff])
                                  : (short)0;
    }
    const int c0 = grp * 4;
    const float bi0 = bias[c0], bi1 = bias[c0 + 1],
                bi2 = bias[c0 + 2], bi3 = bias[c0 + 3];

    for (int y = wv; y < S; y += 8) {
        f32x4 a0 = { bi0, bi1, bi2, bi3 }, a1 = a0, a2 = a0;
#pragma unroll
        for (int s = 0; s < 5; ++s) {
            int koff = 2 * s + kofb;
            if (koff > 8) koff = 8;               // pad tap (A is zero)
            const int dy = koff / 3, dx = koff - dy * 3;
            const int row = (half * BS + (y + dy)) * BS;
            const int x0 = lx + dx;               // chunk 0: lx<=15 < S
            const int x1 = 16 + lx + dx;
            const int x2 = min(32 + lx, S - 1) + dx;
            const bfrag8 b0 = *(const bfrag8*)&inb[(row + x0) * 8];
            const bfrag8 b1 = *(const bfrag8*)&inb[(row + x1) * 8];
            const bfrag8 b2 = *(const bfrag8*)&inb[(row + x2) * 8];
            a0 = __builtin_amdgcn_mfma_f32_16x16x32_bf16(af[s], b0, a0, 0, 0, 0);
            a1 = __builtin_amdgcn_mfma_f32_16x16x32_bf16(af[s], b1, a1, 0, 0, 0);
            a2 = __builtin_amdgcn_mfma_f32_16x16x32_bf16(af[s], b2, a2, 0, 0, 0);
        }
        const int gy = ty0 - hal + y;
        const int ho = c0 >> 3, co = c0 & 7;
        const f32x4 accs[3] = { a0, a1, a2 };
#pragma unroll
        for (int c = 0; c < 3; ++c) {
            const int xr = c * 16 + lx;
            if (xr < S) {
                const int gx = tx0 - hal + xr;
                const bool inim = ((unsigned)gy < (unsigned)HH) &&
                                  ((unsigned)gx < (unsigned)WW);
                short4v st;
#pragma unroll
                for (int i = 0; i < 4; ++i) {
                    float r = accs[c][i];
                    r = (r >= 0.f) ? r : 0.01f * r;
                    st[i] = inim ? f2bf(r) : (short)0;
                }
                *(short4v*)&outb[((ho * BS + y) * BS + xr) * 8 + co] = st;
            }
        }
    }
}

// ---------------------------------------------------------------------------
// Fused predictor: conv_first + 6x conv16 + conv_last+median3+subtract,
// all in LDS. Block = 512 thr (8 waves), one 32x32 output tile, z = batch.
// ---------------------------------------------------------------------------
__global__ __launch_bounds__(512) void k_fused_pred(
    const float* __restrict__ p0, long long s0,
    const float* __restrict__ p1, long long s1,
    const float* __restrict__ xsrc, long long xstride,
    float* __restrict__ outp,
    const float* __restrict__ w0, const float* __restrict__ b0,
    const float* __restrict__ w1, const float* __restrict__ b1,
    const float* __restrict__ w2, const float* __restrict__ b2,
    const float* __restrict__ w3, const float* __restrict__ b3,
    const float* __restrict__ w4, const float* __restrict__ b4,
    const float* __restrict__ w5, const float* __restrict__ b5,
    const float* __restrict__ w6, const float* __restrict__ b6,
    const float* __restrict__ w7, const float* __restrict__ b7)
{
    __shared__ short bufA[2 * BS * BS * 8];   // 67,712 B
    __shared__ short bufB[2 * BS * BS * 8];   // 67,712 B
    __shared__ float fin[2 * FIN * FIN];      // 18,432 B  (total ~154 KB)

    const int tid = threadIdx.x, lane = tid & 63, wv = tid >> 6;
    const int tx0 = blockIdx.x * 32, ty0 = blockIdx.y * 32;
    const long long b = blockIdx.z;

    // ---- stage conv_first input (2 planes, 48x48, origin -8, zero-pad) ----
    const float* pb0 = p0 + b * s0;
    const float* pb1 = p1 + b * s1;
    for (int idx = tid; idx < 2 * FIN * FIN; idx += 512) {
        const int ci = idx / (FIN * FIN), r = idx - ci * FIN * FIN;
        const int yy = r / FIN, xx = r - yy * FIN;
        const int gy = ty0 - 8 + yy, gx = tx0 - 8 + xx;
        float v = 0.f;
        if ((unsigned)gy < (unsigned)HH && (unsigned)gx < (unsigned)WW)
            v = (ci ? pb1 : pb0)[gy * WW + gx];
        fin[idx] = v;
    }

    // ---- conv_first A fragment: K=18 (tap*2+ci), padded to 32 ----
    const int arow = lane & 15, grp = lane >> 4, lx = lane & 15;
    bfrag8 a0f;
#pragma unroll
    for (int j = 0; j < 8; ++j) {
        const int k = grp * 8 + j;
        a0f[j] = (k < 18) ? f2bf(w0[arow * 18 + (k & 1) * 9 + (k >> 1)])
                          : (short)0;
    }
    const int c0 = grp * 4;
    const float fb0 = b0[c0], fb1 = b0[c0 + 1], fb2 = b0[c0 + 2], fb3 = b0[c0 + 3];

    __syncthreads();

    // ---- conv_first: act1 on 46x46 (hal=7) -> bufA ----
    for (int y = wv; y < BS; y += 8) {
        f32x4 ac[3];
#pragma unroll
        for (int c = 0; c < 3; ++c) ac[c] = f32x4{ fb0, fb1, fb2, fb3 };
        bfrag8 bf[3];
#pragma unroll
        for (int c = 0; c < 3; ++c) {
            const int xc = min(c * 16 + lx, BS - 1);
#pragma unroll
            for (int j = 0; j < 8; ++j) {
                const int k = grp * 8 + j;
                short v = 0;
                if (k < 18) {
                    const int tap = k >> 1, dy = tap / 3, dx = tap - dy * 3;
                    v = f2bf(fin[(k & 1) * (FIN * FIN) + (y + dy) * FIN + (xc + dx)]);
                }
                bf[c][j] = v;
            }
        }
#pragma unroll
        for (int c = 0; c < 3; ++c)
            ac[c] = __builtin_amdgcn_mfma_f32_16x16x32_bf16(a0f, bf[c], ac[c], 0, 0, 0);
        const int gy = ty0 - 7 + y;
        const int ho = c0 >> 3, co = c0 & 7;
#pragma unroll
        for (int c = 0; c < 3; ++c) {
            const int xr = c * 16 + lx;
            if (xr < BS) {
                const int gx = tx0 - 7 + xr;
                const bool inim = ((unsigned)gy < (unsigned)HH) &&
                                  ((unsigned)gx < (unsigned)WW);
                short4v st;
#pragma unroll
                for (int i = 0; i < 4; ++i) {
                    float r = ac[c][i];
                    r = (r >= 0.f) ? r : 0.01f * r;
                    st[i] = inim ? f2bf(r) : (short)0;
                }
                *(short4v*)&bufA[((ho * BS + y) * BS + xr) * 8 + co] = st;
            }
        }
    }
    __syncthreads();

    // ---- 6 middle layers, ping-pong ----
    conv16_layer(bufA, bufB, 44, 6, w1, b1, lane, wv, ty0, tx0); __syncthreads();
    conv16_layer(bufB, bufA, 42, 5, w2, b2, lane, wv, ty0, tx0); __syncthreads();
    conv16_layer(bufA, bufB, 40, 4, w3, b3, lane, wv, ty0, tx0); __syncthreads();
    conv16_layer(bufB, bufA, 38, 3, w4, b4, lane, wv, ty0, tx0); __syncthreads();
    conv16_layer(bufA, bufB, 36, 2, w5, b5, lane, wv, ty0, tx0); __syncthreads();
    conv16_layer(bufB, bufA, 34, 1, w6, b6, lane, wv, ty0, tx0); __syncthreads();

    // ---- conv_last (act7 in bufA, S=34): couts 0..2, clip+median3+subtract --
    const int half = grp & 1, cib = half * 8, kofb = grp >> 1;
    bfrag8 lf[5];
#pragma unroll
    for (int s = 0; s < 5; ++s) {
        const int koff = 2 * s + kofb;
#pragma unroll
        for (int j = 0; j < 8; ++j)
            lf[s][j] = (arow < 3 && koff < 9)
                         ? f2bf(w7[(arow * 16 + cib + j) * 9 + koff]) : (short)0;
    }
    const float lb0 = (grp == 0) ? b7[0] : 0.f;
    const float lb1 = (grp == 0) ? b7[1] : 0.f;
    const float lb2 = (grp == 0) ? b7[2] : 0.f;
    const float* xb = xsrc + b * xstride;
    float* ob = outp + b * (long long)HWSZ;

    for (int y = wv; y < 32; y += 8) {
        f32x4 ac0 = { lb0, lb1, lb2, 0.f }, ac1 = ac0;
#pragma unroll
        for (int s = 0; s < 5; ++s) {
            int koff = 2 * s + kofb;
            if (koff > 8) koff = 8;
            const int dy = koff / 3, dx = koff - dy * 3;
            const int row = (half * BS + (y + dy)) * BS;
            const bfrag8 bfa = *(const bfrag8*)&bufA[(row + lx + dx) * 8];
            const bfrag8 bfb = *(const bfrag8*)&bufA[(row + 16 + lx + dx) * 8];
            ac0 = __builtin_amdgcn_mfma_f32_16x16x32_bf16(lf[s], bfa, ac0, 0, 0, 0);
            ac1 = __builtin_amdgcn_mfma_f32_16x16x32_bf16(lf[s], bfb, ac1, 0, 0, 0);
        }
        if (grp == 0) {
            const f32x4 pair[2] = { ac0, ac1 };
#pragma unroll
            for (int c = 0; c < 2; ++c) {
                const int x = c * 16 + lx;
                float y0 = fminf(fmaxf(pair[c][0], -1.f), 1.f);
                float y1 = fminf(fmaxf(pair[c][1], -1.f), 1.f);
                float y2 = fminf(fmaxf(pair[c][2], -1.f), 1.f);
                float med = fmaxf(fminf(y0, fmaxf(y1, y2)), fminf(y1, y2));
                const long long pix = (long long)(ty0 + y) * WW + tx0 + x;
                ob[pix] = xb[pix] - med;
            }
        }
    }
}

// ---------------------------------------------------------------------------
// Stats over x: sum of squares + per-(b,c) 256-bin histogram
// ---------------------------------------------------------------------------
__global__ __launch_bounds__(256) void k_stats_x(
    const float* __restrict__ x, unsigned* __restrict__ hist, float* __restrict__ sums)
{
    const int p = blockIdx.y;
    const float* src = x + (long long)p * HWSZ;
    __shared__ unsigned h[256];
    h[threadIdx.x] = 0;
    __syncthreads();

    float ss = 0.f;
    for (int i = blockIdx.x * 256 + threadIdx.x; i < HWSZ; i += gridDim.x * 256) {
        float v = src[i];
        ss += v * v;
        if (v >= -1.f && v <= 1.f) {
            int idx = (int)floorf((v + 1.f) * 128.f);
            idx = min(max(idx, 0), 255);
            atomicAdd(&h[idx], 1u);
        }
    }
    __syncthreads();
    if (h[threadIdx.x]) atomicAdd(&hist[p * 256 + threadIdx.x], h[threadIdx.x]);

    float bs = blockSum(ss);
    if (threadIdx.x == 0) atomicAdd(&sums[0], bs);
}

// ---------------------------------------------------------------------------
// Stats over deltas of one plane: delta = v - clampgrad_pred
// ---------------------------------------------------------------------------
__global__ __launch_bounds__(256) void k_stats_delta(
    const float* __restrict__ plane, int c,
    unsigned* __restrict__ hist, float* __restrict__ sums)
{
    const int b = blockIdx.y;
    const float* P = plane + (long long)b * HWSZ;
    const int row = b * 3 + c;
    __shared__ unsigned h[256];
    h[threadIdx.x] = 0;
    __syncthreads();

    float ss = 0.f;
    for (int i = blockIdx.x * 256 + threadIdx.x; i < HWSZ; i += gridDim.x * 256) {
        const int y = i >> 9, x = i & (WW - 1);
        float v = P[i];
        float n  = y ? P[i - WW] : 0.f;
        float wv = x ? P[i - 1] : 0.f;
        float nw = (y && x) ? P[i - WW - 1] : 0.f;
        float pr = n + wv - nw;
        pr = fminf(fmaxf(pr, fminf(n, wv)), fmaxf(n, wv));
        float d = v - pr;
        ss += d * d;
        if (d >= -1.f && d <= 1.f) {
            int idx = (int)floorf((d + 1.f) * 128.f);
            idx = min(max(idx, 0), 255);
            atomicAdd(&h[idx], 1u);
        }
    }
    __syncthreads();
    if (h[threadIdx.x]) atomicAdd(&hist[row * 256 + threadIdx.x], h[threadIdx.x]);

    float bs = blockSum(ss);
    if (threadIdx.x == 0) atomicAdd(&sums[1], bs);
}

// ---------------------------------------------------------------------------
// Finalize: entropies + the 4 output scalars
// ---------------------------------------------------------------------------
__global__ __launch_bounds__(256) void k_finalize(
    const unsigned* __restrict__ hist0, const unsigned* __restrict__ hist1,
    const float* __restrict__ sums, float* __restrict__ out)
{
    float e0 = 0.f, e1 = 0.f;
    for (int i = threadIdx.x; i < 48 * 256; i += 256) {
        float p0 = (float)hist0[i] * (1.0f / HWSZ);
        if (p0 > 0.f) e0 -= p0 * log2f(p0);
        float p1 = (float)hist1[i] * (1.0f / HWSZ);
        if (p1 > 0.f) e1 -= p1 * log2f(p1);
    }
    float t0 = blockSum(e0);
    float t1 = blockSum(e1);
    if (threadIdx.x == 0) {
        const float N = (float)BATCH * 3.f * (float)HWSZ;
        out[0] = 128.f * sqrtf(sums[1] / N);   // loss1 (deltas)
        out[1] = 128.f * sqrtf(sums[0] / N);   // loss0 (x)
        out[2] = t0 * (1.f / (8.f * 48.f));    // invcr0
        out[3] = t1 * (1.f / (8.f * 48.f));    // invcr1
    }
}

// ---------------------------------------------------------------------------
extern "C" void kernel_launch(void* const* d_in, const int* in_sizes, int n_in,
                              void* d_out, int out_size, void* d_ws, size_t ws_size,
                              hipStream_t stream) {
    const float* x = (const float*)d_in[0];
    const float* w[8];
    const float* bs[8];
    for (int i = 0; i < 8; ++i) {
        w[i]  = (const float*)d_in[1 + 2 * i];
        bs[i] = (const float*)d_in[2 + 2 * i];
    }

    // Workspace: 3 fp32 planes (50.3 MB) + hists + sums. No activation bufs.
    char* ws = (char*)d_ws;
    size_t o = 0;
    float* rpl = (float*)(ws + o); o += (size_t)BATCH * HWSZ * 4;
    float* gpl = (float*)(ws + o); o += (size_t)BATCH * HWSZ * 4;
    float* bpl = (float*)(ws + o); o += (size_t)BATCH * HWSZ * 4;
    unsigned* hist0 = (unsigned*)(ws + o); o += 48 * 256 * 4;
    unsigned* hist1 = (unsigned*)(ws + o); o += 48 * 256 * 4;
    float* sums = (float*)(ws + o); o += 256;

    hipMemsetAsync(hist0, 0, 48 * 256 * 4 * 2 + 256, stream);

    const dim3 fgrid(WW / 32, HH / 32, BATCH);

    auto predictor = [&](const float* pa, long long sa, const float* pb, long long sb,
                         const float* xs, float* outp) {
        k_fused_pred<<<fgrid, 512, 0, stream>>>(
            pa, sa, pb, sb, xs, 3LL * HWSZ, outp,
            w[0], bs[0], w[1], bs[1], w[2], bs[2], w[3], bs[3],
            w[4], bs[4], w[5], bs[5], w[6], bs[6], w[7], bs[7]);
    };

    // r = x_r - pred(g, b);  g = x_g - pred(r, b);  b = x_b - pred(r, g)
    predictor(x + 1LL * HWSZ, 3LL * HWSZ, x + 2LL * HWSZ, 3LL * HWSZ,
              x + 0LL * HWSZ, rpl);
    predictor(rpl, (long long)HWSZ, x + 2LL * HWSZ, 3LL * HWSZ,
              x + 1LL * HWSZ, gpl);
    predictor(rpl, (long long)HWSZ, gpl, (long long)HWSZ,
              x + 2LL * HWSZ, bpl);

    const dim3 sgrid(64, 48);
    k_stats_x<<<sgrid, 256, 0, stream>>>(x, hist0, sums);
    const dim3 dgrid(64, BATCH);
    k_stats_delta<<<dgrid, 256, 0, stream>>>(rpl, 0, hist1, sums);
    k_stats_delta<<<dgrid, 256, 0, stream>>>(gpl, 1, hist1, sums);
    k_stats_delta<<<dgrid, 256, 0, stream>>>(bpl, 2, hist1, sums);

    k_finalize<<<1, 256, 0, stream>>>(hist0, hist1, sums, (float*)d_out);
}

// Round 10
// 3415.350 us; speedup vs baseline: 1.1895x; 1.1895x over previous
//
#include <hip/hip_runtime.h>
#include <hip/hip_bf16.h>

typedef __hip_bfloat16 hbf16;
typedef __attribute__((ext_vector_type(8))) short bfrag8;
typedef __attribute__((ext_vector_type(4))) short short4v;
typedef __attribute__((ext_vector_type(4))) float f32x4;

#define BATCH 16
#define HH 512
#define WW 512
#define HWSZ (HH * WW)
#define NCHN 16
// Fused predictor: 32x32 output tile, halo recompute, IN-PLACE single buffer.
// act1 extent 46 (halo 7); buf [2 half][46][47pad][8ci] bf16 = 69.2 KB;
// fin bf16 = 9.2 KB; total 78.4 KB -> 2 blocks/CU.
#define BS 46
#define BSP 47
#define FIN 48

__device__ __forceinline__ short f2bf(float f) {
    hbf16 h = __float2bfloat16(f);
    return *(short*)&h;
}

// ---------------------------------------------------------------------------
// Block-wide sum reduction (256 threads = 4 waves of 64)
// ---------------------------------------------------------------------------
__device__ __forceinline__ float blockSum(float v) {
#pragma unroll
    for (int o = 32; o > 0; o >>= 1) v += __shfl_down(v, o, 64);
    __shared__ float sh[4];
    const int lane = threadIdx.x & 63, wid = threadIdx.x >> 6;
    if (lane == 0) sh[wid] = v;
    __syncthreads();
    float r = 0.f;
    if (threadIdx.x == 0) r = sh[0] + sh[1] + sh[2] + sh[3];
    __syncthreads();
    return r;
}

// ---------------------------------------------------------------------------
// One in-place conv16 layer (LDS buf -> same buf). Band discipline:
// per 8-row band: compute (reads rows 8b..8b+9, all pre-band values) ->
// barrier -> write rows 8b..8b+7 -> barrier. out[y] = f(in[y..y+2]).
// MFMA mapping identical to the HW-verified R7 kernel.
// ---------------------------------------------------------------------------
__device__ __forceinline__ void conv16_inplace(
    short* buf, int S /*out extent*/, int hal,
    const float* __restrict__ w, const float* __restrict__ bias,
    int lane, int wv, int ty0, int tx0)
{
    const int arow = lane & 15, grp = lane >> 4, lx = lane & 15;
    const int half = grp & 1, cib = half * 8, kofb = grp >> 1;
    bfrag8 af[5];
#pragma unroll
    for (int s = 0; s < 5; ++s) {
        const int koff = 2 * s + kofb;
#pragma unroll
        for (int j = 0; j < 8; ++j)
            af[s][j] = (koff < 9) ? f2bf(w[(arow * 16 + cib + j) * 9 + koff])
                                  : (short)0;
    }
    const int c0 = grp * 4;
    const float bi0 = bias[c0], bi1 = bias[c0 + 1],
                bi2 = bias[c0 + 2], bi3 = bias[c0 + 3];
    const int ho = c0 >> 3, co = c0 & 7;
    const int nb = (S + 7) >> 3;

    for (int b = 0; b < nb; ++b) {
        const int y = b * 8 + wv;
        const bool act = (y < S);
        short4v st[3];
        if (act) {
            f32x4 a0 = { bi0, bi1, bi2, bi3 }, a1 = a0, a2 = a0;
#pragma unroll
            for (int s = 0; s < 5; ++s) {
                int koff = 2 * s + kofb;
                if (koff > 8) koff = 8;           // pad tap (A is zero)
                const int dy = koff / 3, dx = koff - dy * 3;
                const int row = (half * BS + (y + dy)) * BSP;
                const bfrag8 b0 = *(const bfrag8*)&buf[(row + lx + dx) * 8];
                const bfrag8 b1 = *(const bfrag8*)&buf[(row + 16 + lx + dx) * 8];
                const int x2 = min(32 + lx, S - 1) + dx;
                const bfrag8 b2 = *(const bfrag8*)&buf[(row + x2) * 8];
                a0 = __builtin_amdgcn_mfma_f32_16x16x32_bf16(af[s], b0, a0, 0, 0, 0);
                a1 = __builtin_amdgcn_mfma_f32_16x16x32_bf16(af[s], b1, a1, 0, 0, 0);
                a2 = __builtin_amdgcn_mfma_f32_16x16x32_bf16(af[s], b2, a2, 0, 0, 0);
            }
            const int gy = ty0 - hal + y;
            const f32x4 accs[3] = { a0, a1, a2 };
#pragma unroll
            for (int c = 0; c < 3; ++c) {
                const int xr = c * 16 + lx;
                const int gx = tx0 - hal + xr;
                const bool inim = ((unsigned)gy < (unsigned)HH) &&
                                  ((unsigned)gx < (unsigned)WW);
#pragma unroll
                for (int i = 0; i < 4; ++i) {
                    float r = accs[c][i];
                    r = (r >= 0.f) ? r : 0.01f * r;
                    st[c][i] = inim ? f2bf(r) : (short)0;
                }
            }
        }
        __syncthreads();
        if (act) {
#pragma unroll
            for (int c = 0; c < 3; ++c) {
                const int xr = c * 16 + lx;
                if (xr < S)
                    *(short4v*)&buf[((ho * BS + y) * BSP + xr) * 8 + co] = st[c];
            }
        }
        __syncthreads();
    }
}

// ---------------------------------------------------------------------------
// Fused predictor: conv_first + 6x conv16 (in-place) + conv_last + median3
// + subtract. Block = 512 thr (8 waves), one 32x32 output tile, z = batch.
// LDS 78.4 KB -> 2 blocks/CU.
// ---------------------------------------------------------------------------
__global__ __launch_bounds__(512, 4) void k_fused_pred(
    const float* __restrict__ p0, long long s0,
    const float* __restrict__ p1, long long s1,
    const float* __restrict__ xsrc, long long xstride,
    float* __restrict__ outp,
    const float* __restrict__ w0, const float* __restrict__ b0,
    const float* __restrict__ w1, const float* __restrict__ b1,
    const float* __restrict__ w2, const float* __restrict__ b2,
    const float* __restrict__ w3, const float* __restrict__ b3,
    const float* __restrict__ w4, const float* __restrict__ b4,
    const float* __restrict__ w5, const float* __restrict__ b5,
    const float* __restrict__ w6, const float* __restrict__ b6,
    const float* __restrict__ w7, const float* __restrict__ b7)
{
    __shared__ short buf[2 * BS * BSP * 8];   // 69,184 B
    __shared__ short fin[2 * FIN * FIN];      //  9,216 B  (total 78.4 KB)

    const int tid = threadIdx.x, lane = tid & 63, wv = tid >> 6;
    const int tx0 = blockIdx.x * 32, ty0 = blockIdx.y * 32;
    const long long b = blockIdx.z;

    // ---- stage conv_first input (2 planes, 48x48, origin -8, zero-pad) ----
    const float* pb0 = p0 + b * s0;
    const float* pb1 = p1 + b * s1;
    for (int idx = tid; idx < 2 * FIN * FIN; idx += 512) {
        const int ci = idx / (FIN * FIN), r = idx - ci * FIN * FIN;
        const int yy = r / FIN, xx = r - yy * FIN;
        const int gy = ty0 - 8 + yy, gx = tx0 - 8 + xx;
        float v = 0.f;
        if ((unsigned)gy < (unsigned)HH && (unsigned)gx < (unsigned)WW)
            v = (ci ? pb1 : pb0)[gy * WW + gx];
        fin[idx] = f2bf(v);
    }

    // ---- conv_first A fragment: K=18 (tap*2+ci), padded to 32 ----
    const int arow = lane & 15, grp = lane >> 4, lx = lane & 15;
    bfrag8 a0f;
#pragma unroll
    for (int j = 0; j < 8; ++j) {
        const int k = grp * 8 + j;
        a0f[j] = (k < 18) ? f2bf(w0[arow * 18 + (k & 1) * 9 + (k >> 1)])
                          : (short)0;
    }
    const int c0 = grp * 4;
    const float fb0 = b0[c0], fb1 = b0[c0 + 1], fb2 = b0[c0 + 2], fb3 = b0[c0 + 3];

    __syncthreads();

    // ---- conv_first: act1 on 46x46 (hal=7) -> buf (no alias, no bands) ----
    for (int y = wv; y < BS; y += 8) {
        f32x4 ac[3];
#pragma unroll
        for (int c = 0; c < 3; ++c) ac[c] = f32x4{ fb0, fb1, fb2, fb3 };
        bfrag8 bf[3];
#pragma unroll
        for (int c = 0; c < 3; ++c) {
            const int xc = min(c * 16 + lx, BS - 1);
#pragma unroll
            for (int j = 0; j < 8; ++j) {
                const int k = grp * 8 + j;
                short v = 0;
                if (k < 18) {
                    const int tap = k >> 1, dy = tap / 3, dx = tap - dy * 3;
                    v = fin[(k & 1) * (FIN * FIN) + (y + dy) * FIN + (xc + dx)];
                }
                bf[c][j] = v;
            }
        }
#pragma unroll
        for (int c = 0; c < 3; ++c)
            ac[c] = __builtin_amdgcn_mfma_f32_16x16x32_bf16(a0f, bf[c], ac[c], 0, 0, 0);
        const int gy = ty0 - 7 + y;
        const int ho = c0 >> 3, co = c0 & 7;
#pragma unroll
        for (int c = 0; c < 3; ++c) {
            const int xr = c * 16 + lx;
            if (xr < BS) {
                const int gx = tx0 - 7 + xr;
                const bool inim = ((unsigned)gy < (unsigned)HH) &&
                                  ((unsigned)gx < (unsigned)WW);
                short4v st;
#pragma unroll
                for (int i = 0; i < 4; ++i) {
                    float r = ac[c][i];
                    r = (r >= 0.f) ? r : 0.01f * r;
                    st[i] = inim ? f2bf(r) : (short)0;
                }
                *(short4v*)&buf[((ho * BS + y) * BSP + xr) * 8 + co] = st;
            }
        }
    }
    __syncthreads();

    // ---- 6 middle layers, in-place ----
    conv16_inplace(buf, 44, 6, w1, b1, lane, wv, ty0, tx0);
    conv16_inplace(buf, 42, 5, w2, b2, lane, wv, ty0, tx0);
    conv16_inplace(buf, 40, 4, w3, b3, lane, wv, ty0, tx0);
    conv16_inplace(buf, 38, 3, w4, b4, lane, wv, ty0, tx0);
    conv16_inplace(buf, 36, 2, w5, b5, lane, wv, ty0, tx0);
    conv16_inplace(buf, 34, 1, w6, b6, lane, wv, ty0, tx0);

    // ---- conv_last (extent 34 in buf): couts 0..2, clip+median3+subtract ----
    const int half = grp & 1, cib = half * 8, kofb = grp >> 1;
    bfrag8 lf[5];
#pragma unroll
    for (int s = 0; s < 5; ++s) {
        const int koff = 2 * s + kofb;
#pragma unroll
        for (int j = 0; j < 8; ++j)
            lf[s][j] = (arow < 3 && koff < 9)
                         ? f2bf(w7[(arow * 16 + cib + j) * 9 + koff]) : (short)0;
    }
    const float lb0 = (grp == 0) ? b7[0] : 0.f;
    const float lb1 = (grp == 0) ? b7[1] : 0.f;
    const float lb2 = (grp == 0) ? b7[2] : 0.f;
    const float* xb = xsrc + b * xstride;
    float* ob = outp + b * (long long)HWSZ;

    for (int y = wv; y < 32; y += 8) {
        f32x4 ac0 = { lb0, lb1, lb2, 0.f }, ac1 = ac0;
#pragma unroll
        for (int s = 0; s < 5; ++s) {
            int koff = 2 * s + kofb;
            if (koff > 8) koff = 8;
            const int dy = koff / 3, dx = koff - dy * 3;
            const int row = (half * BS + (y + dy)) * BSP;
            const bfrag8 bfa = *(const bfrag8*)&buf[(row + lx + dx) * 8];
            const bfrag8 bfb = *(const bfrag8*)&buf[(row + 16 + lx + dx) * 8];
            ac0 = __builtin_amdgcn_mfma_f32_16x16x32_bf16(lf[s], bfa, ac0, 0, 0, 0);
            ac1 = __builtin_amdgcn_mfma_f32_16x16x32_bf16(lf[s], bfb, ac1, 0, 0, 0);
        }
        if (grp == 0) {
            const f32x4 pair[2] = { ac0, ac1 };
#pragma unroll
            for (int c = 0; c < 2; ++c) {
                const int x = c * 16 + lx;
                float y0 = fminf(fmaxf(pair[c][0], -1.f), 1.f);
                float y1 = fminf(fmaxf(pair[c][1], -1.f), 1.f);
                float y2 = fminf(fmaxf(pair[c][2], -1.f), 1.f);
                float med = fmaxf(fminf(y0, fmaxf(y1, y2)), fminf(y1, y2));
                const long long pix = (long long)(ty0 + y) * WW + tx0 + x;
                ob[pix] = xb[pix] - med;
            }
        }
    }
}

// ---------------------------------------------------------------------------
// Stats over x: sum of squares + per-(b,c) 256-bin histogram
// ---------------------------------------------------------------------------
__global__ __launch_bounds__(256) void k_stats_x(
    const float* __restrict__ x, unsigned* __restrict__ hist, float* __restrict__ sums)
{
    const int p = blockIdx.y;
    const float* src = x + (long long)p * HWSZ;
    __shared__ unsigned h[256];
    h[threadIdx.x] = 0;
    __syncthreads();

    float ss = 0.f;
    for (int i = blockIdx.x * 256 + threadIdx.x; i < HWSZ; i += gridDim.x * 256) {
        float v = src[i];
        ss += v * v;
        if (v >= -1.f && v <= 1.f) {
            int idx = (int)floorf((v + 1.f) * 128.f);
            idx = min(max(idx, 0), 255);
            atomicAdd(&h[idx], 1u);
        }
    }
    __syncthreads();
    if (h[threadIdx.x]) atomicAdd(&hist[p * 256 + threadIdx.x], h[threadIdx.x]);

    float bs = blockSum(ss);
    if (threadIdx.x == 0) atomicAdd(&sums[0], bs);
}

// ---------------------------------------------------------------------------
// Stats over deltas of one plane: delta = v - clampgrad_pred
// ---------------------------------------------------------------------------
__global__ __launch_bounds__(256) void k_stats_delta(
    const float* __restrict__ plane, int c,
    unsigned* __restrict__ hist, float* __restrict__ sums)
{
    const int b = blockIdx.y;
    const float* P = plane + (long long)b * HWSZ;
    const int row = b * 3 + c;
    __shared__ unsigned h[256];
    h[threadIdx.x] = 0;
    __syncthreads();

    float ss = 0.f;
    for (int i = blockIdx.x * 256 + threadIdx.x; i < HWSZ; i += gridDim.x * 256) {
        const int y = i >> 9, x = i & (WW - 1);
        float v = P[i];
        float n  = y ? P[i - WW] : 0.f;
        float wv = x ? P[i - 1] : 0.f;
        float nw = (y && x) ? P[i - WW - 1] : 0.f;
        float pr = n + wv - nw;
        pr = fminf(fmaxf(pr, fminf(n, wv)), fmaxf(n, wv));
        float d = v - pr;
        ss += d * d;
        if (d >= -1.f && d <= 1.f) {
            int idx = (int)floorf((d + 1.f) * 128.f);
            idx = min(max(idx, 0), 255);
            atomicAdd(&h[idx], 1u);
        }
    }
    __syncthreads();
    if (h[threadIdx.x]) atomicAdd(&hist[row * 256 + threadIdx.x], h[threadIdx.x]);

    float bs = blockSum(ss);
    if (threadIdx.x == 0) atomicAdd(&sums[1], bs);
}

// ---------------------------------------------------------------------------
// Finalize: entropies + the 4 output scalars
// ---------------------------------------------------------------------------
__global__ __launch_bounds__(256) void k_finalize(
    const unsigned* __restrict__ hist0, const unsigned* __restrict__ hist1,
    const float* __restrict__ sums, float* __restrict__ out)
{
    float e0 = 0.f, e1 = 0.f;
    for (int i = threadIdx.x; i < 48 * 256; i += 256) {
        float p0 = (float)hist0[i] * (1.0f / HWSZ);
        if (p0 > 0.f) e0 -= p0 * log2f(p0);
        float p1 = (float)hist1[i] * (1.0f / HWSZ);
        if (p1 > 0.f) e1 -= p1 * log2f(p1);
    }
    float t0 = blockSum(e0);
    float t1 = blockSum(e1);
    if (threadIdx.x == 0) {
        const float N = (float)BATCH * 3.f * (float)HWSZ;
        out[0] = 128.f * sqrtf(sums[1] / N);   // loss1 (deltas)
        out[1] = 128.f * sqrtf(sums[0] / N);   // loss0 (x)
        out[2] = t0 * (1.f / (8.f * 48.f));    // invcr0
        out[3] = t1 * (1.f / (8.f * 48.f));    // invcr1
    }
}

// ---------------------------------------------------------------------------
extern "C" void kernel_launch(void* const* d_in, const int* in_sizes, int n_in,
                              void* d_out, int out_size, void* d_ws, size_t ws_size,
                              hipStream_t stream) {
    const float* x = (const float*)d_in[0];
    const float* w[8];
    const float* bs[8];
    for (int i = 0; i < 8; ++i) {
        w[i]  = (const float*)d_in[1 + 2 * i];
        bs[i] = (const float*)d_in[2 + 2 * i];
    }

    // Workspace: 3 fp32 planes (50.3 MB) + hists + sums. No activation bufs.
    char* ws = (char*)d_ws;
    size_t o = 0;
    float* rpl = (float*)(ws + o); o += (size_t)BATCH * HWSZ * 4;
    float* gpl = (float*)(ws + o); o += (size_t)BATCH * HWSZ * 4;
    float* bpl = (float*)(ws + o); o += (size_t)BATCH * HWSZ * 4;
    unsigned* hist0 = (unsigned*)(ws + o); o += 48 * 256 * 4;
    unsigned* hist1 = (unsigned*)(ws + o); o += 48 * 256 * 4;
    float* sums = (float*)(ws + o); o += 256;

    hipMemsetAsync(hist0, 0, 48 * 256 * 4 * 2 + 256, stream);

    const dim3 fgrid(WW / 32, HH / 32, BATCH);

    auto predictor = [&](const float* pa, long long sa, const float* pb, long long sb,
                         const float* xs, float* outp) {
        k_fused_pred<<<fgrid, 512, 0, stream>>>(
            pa, sa, pb, sb, xs, 3LL * HWSZ, outp,
            w[0], bs[0], w[1], bs[1], w[2], bs[2], w[3], bs[3],
            w[4], bs[4], w[5], bs[5], w[6], bs[6], w[7], bs[7]);
    };

    // r = x_r - pred(g, b);  g = x_g - pred(r, b);  b = x_b - pred(r, g)
    predictor(x + 1LL * HWSZ, 3LL * HWSZ, x + 2LL * HWSZ, 3LL * HWSZ,
              x + 0LL * HWSZ, rpl);
    predictor(rpl, (long long)HWSZ, x + 2LL * HWSZ, 3LL * HWSZ,
              x + 1LL * HWSZ, gpl);
    predictor(rpl, (long long)HWSZ, gpl, (long long)HWSZ,
              x + 2LL * HWSZ, bpl);

    const dim3 sgrid(64, 48);
    k_stats_x<<<sgrid, 256, 0, stream>>>(x, hist0, sums);
    const dim3 dgrid(64, BATCH);
    k_stats_delta<<<dgrid, 256, 0, stream>>>(rpl, 0, hist1, sums);
    k_stats_delta<<<dgrid, 256, 0, stream>>>(gpl, 1, hist1, sums);
    k_stats_delta<<<dgrid, 256, 0, stream>>>(bpl, 2, hist1, sums);

    k_finalize<<<1, 256, 0, stream>>>(hist0, hist1, sums, (float*)d_out);
}